// Round 1
// baseline (15474.434 us; speedup 1.0000x reference)
//
#include <hip/hip_runtime.h>
#include <hip/hip_bf16.h>

// Problem constants
#define BB 8
#define NN 100
#define DIMM 256
#define HEADSS 8
#define HDD 32
#define FFNN 2048
#define MM 16384               // H*W = 128*128
#define ROWS (BB*NN)           // 800
#define CTX_ROWS (BB*MM)       // 131072
#define SCALE 0.17677669529663689f   // 1/sqrt(32)

// ---------------- LayerNorm (dim=256), one block per row ----------------
__global__ void ln_kernel(const float* __restrict__ x, const float* __restrict__ g,
                          const float* __restrict__ beta, float* __restrict__ y) {
    int row = blockIdx.x;
    int t = threadIdx.x;
    float v = x[row * 256 + t];
    __shared__ float red[256];
    red[t] = v; __syncthreads();
    for (int s = 128; s > 0; s >>= 1) { if (t < s) red[t] += red[t + s]; __syncthreads(); }
    float mu = red[0] * (1.0f / 256.0f);
    __syncthreads();
    float d = v - mu;
    red[t] = d * d; __syncthreads();
    for (int s = 128; s > 0; s >>= 1) { if (t < s) red[t] += red[t + s]; __syncthreads(); }
    float var = red[0] * (1.0f / 256.0f);
    float r = rsqrtf(var + 1e-5f);
    y[row * 256 + t] = d * r * g[t] + beta[t];
}

// ---------------- Generic projection: out[r][c] = act(in[r]·w[c] + bias[c]) (+res) ----
template<bool GELU, bool RES>
__global__ void proj_kernel(const float* __restrict__ in, const float* __restrict__ w,
                            const float* __restrict__ bias, const float* __restrict__ res,
                            float* __restrict__ out, int rows, int K, int C) {
    int idx = blockIdx.x * 256 + threadIdx.x;
    if (idx >= rows * C) return;
    int r = idx / C;
    int c = idx - r * C;
    const float4* inr = reinterpret_cast<const float4*>(in + (size_t)r * K);
    const float4* wr  = reinterpret_cast<const float4*>(w  + (size_t)c * K);
    float acc = 0.0f;
    int k4 = K >> 2;
    for (int k = 0; k < k4; k++) {
        float4 a = inr[k], b = wr[k];
        acc += a.x * b.x + a.y * b.y + a.z * b.z + a.w * b.w;
    }
    acc += bias[c];
    if (GELU) acc = 0.5f * acc * (1.0f + erff(acc * 0.70710678118654752f));
    if (RES)  acc += res[idx];
    out[idx] = acc;
}

// ---------------- KV projection: kv[r][c] = ctx[r]·w[c] + bias[c], stored bf16 ------
__global__ void kv_proj_kernel(const float* __restrict__ ctx, const float* __restrict__ w,
                               const float* __restrict__ bias, __hip_bfloat16* __restrict__ kv) {
    int idx = blockIdx.x * 256 + threadIdx.x;   // r*512 + c, max 67.1M fits int
    int r = idx >> 9;
    int c = idx & 511;
    const float4* inr = reinterpret_cast<const float4*>(ctx + (size_t)r * 256);
    const float4* wr  = reinterpret_cast<const float4*>(w   + (size_t)c * 256);
    float acc = 0.0f;
    #pragma unroll 8
    for (int k = 0; k < 64; k++) {
        float4 a = inr[k], b = wr[k];
        acc += a.x * b.x + a.y * b.y + a.z * b.z + a.w * b.w;
    }
    kv[(size_t)idx] = __float2bfloat16(acc + bias[c]);
}

__device__ inline float bf_lo(unsigned int u) {
    union { unsigned int i; float f; } cv; cv.i = u << 16; return cv.f;
}
__device__ inline float bf_hi(unsigned int u) {
    union { unsigned int i; float f; } cv; cv.i = u & 0xffff0000u; return cv.f;
}

// ---------------- Masked cross-attention: one block per (b, h, n) row ----------------
// q: [b,n,256] (head-major within row), kv: bf16 [b, m, 512] (k: c<256, v: c>=256)
// mask: int32 [b, n, 16384]; o: [b,n,256]
__global__ void xattn_kernel(const float* __restrict__ q, const __hip_bfloat16* __restrict__ kv,
                             const int* __restrict__ mask, float* __restrict__ o) {
    int n = blockIdx.x, h = blockIdx.y, b = blockIdx.z;
    int t = threadIdx.x;
    __shared__ float qs[32];
    __shared__ float dots[16384];   // 64 KB
    __shared__ float red[256];
    __shared__ float ored[16 * 32];
    if (t < 32) qs[t] = q[((size_t)(b * NN + n)) * 256 + h * 32 + t] * SCALE;
    __syncthreads();

    const __hip_bfloat16* kvb = kv + (size_t)b * MM * 512;
    const int* mrow = mask + ((size_t)(b * NN + n)) * MM;

    // pass 1: dots + running max
    float lmax = -INFINITY;
    for (int m = t; m < MM; m += 256) {
        float s;
        if (mrow[m] == 0) {
            s = -INFINITY;
        } else {
            const uint4* kp = reinterpret_cast<const uint4*>(kvb + (size_t)m * 512 + h * 32);
            float acc = 0.0f;
            #pragma unroll
            for (int i = 0; i < 4; i++) {
                uint4 u = kp[i];
                acc += qs[i*8+0] * bf_lo(u.x) + qs[i*8+1] * bf_hi(u.x)
                     + qs[i*8+2] * bf_lo(u.y) + qs[i*8+3] * bf_hi(u.y)
                     + qs[i*8+4] * bf_lo(u.z) + qs[i*8+5] * bf_hi(u.z)
                     + qs[i*8+6] * bf_lo(u.w) + qs[i*8+7] * bf_hi(u.w);
            }
            s = acc;
        }
        dots[m] = s;
        lmax = fmaxf(lmax, s);
    }
    red[t] = lmax; __syncthreads();
    for (int s = 128; s > 0; s >>= 1) { if (t < s) red[t] = fmaxf(red[t], red[t + s]); __syncthreads(); }
    float gmax = red[0];
    __syncthreads();

    // pass 2: exp + sum
    float lsum = 0.0f;
    for (int m = t; m < MM; m += 256) {
        float d = dots[m];
        float p = (d == -INFINITY) ? 0.0f : __expf(d - gmax);
        dots[m] = p;
        lsum += p;
    }
    red[t] = lsum; __syncthreads();
    for (int s = 128; s > 0; s >>= 1) { if (t < s) red[t] += red[t + s]; __syncthreads(); }
    float inv = 1.0f / red[0];
    __syncthreads();

    // pass 3: o[d] = sum_m p[m] * v[m][d];  16 m-groups x 16 d-pairs
    int g = t >> 4;          // 0..15
    int dp = t & 15;         // d pair: (2dp, 2dp+1)
    float acc0 = 0.0f, acc1 = 0.0f;
    for (int m = g; m < MM; m += 16) {
        float p = dots[m];
        unsigned int u = *reinterpret_cast<const unsigned int*>(kvb + (size_t)m * 512 + 256 + h * 32 + 2 * dp);
        acc0 += p * bf_lo(u);
        acc1 += p * bf_hi(u);
    }
    ored[g * 32 + 2 * dp]     = acc0;
    ored[g * 32 + 2 * dp + 1] = acc1;
    __syncthreads();
    if (t < 32) {
        float s = 0.0f;
        #pragma unroll
        for (int g2 = 0; g2 < 16; g2++) s += ored[g2 * 32 + t];
        o[((size_t)(b * NN + n)) * 256 + h * 32 + t] = s * inv;
    }
}

// ---------------- Self-attention over seq axis = b (8), one block per n -------------
// qkv: [b, n, 768]; so: [b, n, 256]
__global__ void sattn_kernel(const float* __restrict__ qkv, float* __restrict__ so) {
    int n = blockIdx.x;
    int t = threadIdx.x;
    __shared__ float sq[8][256], sk[8][256], sv[8][256];
    __shared__ float S[512];   // [h][i][j]
    for (int idx = t; idx < 8 * 768; idx += 256) {
        int i = idx / 768, c = idx - i * 768;
        float v = qkv[((size_t)(i * NN + n)) * 768 + c];
        if (c < 256) sq[i][c] = v * SCALE;
        else if (c < 512) sk[i][c - 256] = v;
        else sv[i][c - 512] = v;
    }
    __syncthreads();
    for (int idx = t; idx < 512; idx += 256) {
        int h = idx >> 6, i = (idx >> 3) & 7, j = idx & 7;
        float acc = 0.0f;
        #pragma unroll
        for (int d = 0; d < 32; d++) acc += sq[i][h * 32 + d] * sk[j][h * 32 + d];
        S[idx] = acc;
    }
    __syncthreads();
    if (t < 64) {
        int h = t >> 3, i = t & 7;
        float* row = &S[h * 64 + i * 8];
        float mx = row[0];
        #pragma unroll
        for (int j = 1; j < 8; j++) mx = fmaxf(mx, row[j]);
        float sum = 0.0f;
        #pragma unroll
        for (int j = 0; j < 8; j++) { row[j] = __expf(row[j] - mx); sum += row[j]; }
        float inv = 1.0f / sum;
        #pragma unroll
        for (int j = 0; j < 8; j++) row[j] *= inv;
    }
    __syncthreads();
    int c = t, h = t >> 5;
    #pragma unroll
    for (int i = 0; i < 8; i++) {
        float acc = 0.0f;
        #pragma unroll
        for (int j = 0; j < 8; j++) acc += S[h * 64 + i * 8 + j] * sv[j][c];
        so[((size_t)(i * NN + n)) * 256 + c] = acc;
    }
}

extern "C" void kernel_launch(void* const* d_in, const int* in_sizes, int n_in,
                              void* d_out, int out_size, void* d_ws, size_t ws_size,
                              hipStream_t stream) {
    const float* x      = (const float*)d_in[0];
    const float* ctx    = (const float*)d_in[1];
    const int*   mask   = (const int*)  d_in[2];
    const float* mq_w   = (const float*)d_in[3];
    const float* mq_b   = (const float*)d_in[4];
    const float* mkv_w  = (const float*)d_in[5];
    const float* mkv_b  = (const float*)d_in[6];
    const float* mproj_w= (const float*)d_in[7];
    const float* mproj_b= (const float*)d_in[8];
    const float* in_w   = (const float*)d_in[9];
    const float* in_b   = (const float*)d_in[10];
    const float* out_w  = (const float*)d_in[11];
    const float* out_b  = (const float*)d_in[12];
    const float* w1     = (const float*)d_in[13];
    const float* b1     = (const float*)d_in[14];
    const float* w2     = (const float*)d_in[15];
    const float* b2     = (const float*)d_in[16];
    const float* n1_g   = (const float*)d_in[17];
    const float* n1_b   = (const float*)d_in[18];
    const float* n2_g   = (const float*)d_in[19];
    const float* n2_b   = (const float*)d_in[20];
    const float* n3_g   = (const float*)d_in[21];
    const float* n3_b   = (const float*)d_in[22];
    const float* n4_g   = (const float*)d_in[23];
    const float* n4_b   = (const float*)d_in[24];

    float* ws = (float*)d_ws;
    // fp32 workspace layout (floats)
    float* Y1  = ws + 0;         // 204800
    float* Q   = ws + 204800;    // 204800
    float* O   = ws + 409600;    // 204800
    float* X1  = ws + 614400;    // 204800
    float* Y2  = ws + 819200;    // 204800
    float* QKV = ws + 1024000;   // 614400
    float* SO  = ws + 1638400;   // 204800
    float* X2  = ws + 1843200;   // 204800
    float* Y3  = ws + 2048000;   // 204800
    float* F1  = ws + 2252800;   // 1638400
    float* X3  = ws + 3891200;   // 204800
    __hip_bfloat16* KV = (__hip_bfloat16*)((char*)d_ws + 16384000); // 134,217,728 B
    // total ws need ~150.6 MB

    float* out = (float*)d_out;

    // 1) y1 = ln(x, n1)
    ln_kernel<<<ROWS, 256, 0, stream>>>(x, n1_g, n1_b, Y1);
    // 2) q = y1 @ mq_w.T + mq_b
    proj_kernel<false, false><<<(ROWS * 256 + 255) / 256, 256, 0, stream>>>(
        Y1, mq_w, mq_b, nullptr, Q, ROWS, 256, 256);
    // 3) kv = ctx @ mkv_w.T + mkv_b (bf16)
    kv_proj_kernel<<<(CTX_ROWS * 512) / 256, 256, 0, stream>>>(ctx, mkv_w, mkv_b, KV);
    // 4) cross-attention
    {
        dim3 grid(NN, HEADSS, BB);
        xattn_kernel<<<grid, 256, 0, stream>>>(Q, KV, mask, O);
    }
    // 5) x1 = x + o @ mproj_w.T + mproj_b
    proj_kernel<false, true><<<(ROWS * 256 + 255) / 256, 256, 0, stream>>>(
        O, mproj_w, mproj_b, x, X1, ROWS, 256, 256);
    // 6) y2 = ln(x1, n2)
    ln_kernel<<<ROWS, 256, 0, stream>>>(X1, n2_g, n2_b, Y2);
    // 7) qkv = y2 @ in_w.T + in_b
    proj_kernel<false, false><<<(ROWS * 768 + 255) / 256, 256, 0, stream>>>(
        Y2, in_w, in_b, nullptr, QKV, ROWS, 256, 768);
    // 8) self-attention over seq axis b
    sattn_kernel<<<NN, 256, 0, stream>>>(QKV, SO);
    // 9) x2 = x1 + so @ out_w.T + out_b
    proj_kernel<false, true><<<(ROWS * 256 + 255) / 256, 256, 0, stream>>>(
        SO, out_w, out_b, X1, X2, ROWS, 256, 256);
    // 10) y3 = ln(x2, n3)
    ln_kernel<<<ROWS, 256, 0, stream>>>(X2, n3_g, n3_b, Y3);
    // 11) f1 = gelu(y3 @ w1.T + b1)
    proj_kernel<true, false><<<(ROWS * FFNN + 255) / 256, 256, 0, stream>>>(
        Y3, w1, b1, nullptr, F1, ROWS, 256, FFNN);
    // 12) x3 = x2 + f1 @ w2.T + b2
    proj_kernel<false, true><<<(ROWS * 256 + 255) / 256, 256, 0, stream>>>(
        F1, w2, b2, X2, X3, ROWS, FFNN, 256);
    // 13) out = ln(x3, n4)
    ln_kernel<<<ROWS, 256, 0, stream>>>(X3, n4_g, n4_b, out);
}

// Round 2
// 3843.578 us; speedup vs baseline: 4.0260x; 4.0260x over previous
//
#include <hip/hip_runtime.h>
#include <hip/hip_bf16.h>

// Problem constants
#define BB 8
#define NN 100
#define DIMM 256
#define HEADSS 8
#define HDD 32
#define FFNN 2048
#define MM 16384               // H*W = 128*128
#define ROWS (BB*NN)           // 800
#define CTX_ROWS (BB*MM)       // 131072
#define SCALE 0.17677669529663689f   // 1/sqrt(32)

typedef __attribute__((ext_vector_type(8))) short s16x8;
typedef __attribute__((ext_vector_type(4))) float f32x4;

__device__ inline ushort f2bf(float f) {
    union { float f; unsigned u; } c; c.f = f;
    unsigned r = c.u + 0x7fffu + ((c.u >> 16) & 1u);
    return (ushort)(r >> 16);
}
__device__ inline float bf2f(ushort u) {
    union { unsigned i; float f; } c; c.i = ((unsigned)u) << 16; return c.f;
}
__device__ inline float bf_lo(unsigned int u) {
    union { unsigned int i; float f; } cv; cv.i = u << 16; return cv.f;
}
__device__ inline float bf_hi(unsigned int u) {
    union { unsigned int i; float f; } cv; cv.i = u & 0xffff0000u; return cv.f;
}

// ---------------- LayerNorm (dim=256), one block per row ----------------
__global__ void ln_kernel(const float* __restrict__ x, const float* __restrict__ g,
                          const float* __restrict__ beta, float* __restrict__ y) {
    int row = blockIdx.x;
    int t = threadIdx.x;
    float v = x[row * 256 + t];
    __shared__ float red[256];
    red[t] = v; __syncthreads();
    for (int s = 128; s > 0; s >>= 1) { if (t < s) red[t] += red[t + s]; __syncthreads(); }
    float mu = red[0] * (1.0f / 256.0f);
    __syncthreads();
    float d = v - mu;
    red[t] = d * d; __syncthreads();
    for (int s = 128; s > 0; s >>= 1) { if (t < s) red[t] += red[t + s]; __syncthreads(); }
    float var = red[0] * (1.0f / 256.0f);
    float r = rsqrtf(var + 1e-5f);
    y[row * 256 + t] = d * r * g[t] + beta[t];
}

// ---------------- Generic projection: out[r][c] = act(in[r]·w[c] + bias[c]) (+res) ----
template<bool GELU, bool RES>
__global__ void proj_kernel(const float* __restrict__ in, const float* __restrict__ w,
                            const float* __restrict__ bias, const float* __restrict__ res,
                            float* __restrict__ out, int rows, int K, int C) {
    int idx = blockIdx.x * 256 + threadIdx.x;
    if (idx >= rows * C) return;
    int r = idx / C;
    int c = idx - r * C;
    const float4* inr = reinterpret_cast<const float4*>(in + (size_t)r * K);
    const float4* wr  = reinterpret_cast<const float4*>(w  + (size_t)c * K);
    float acc = 0.0f;
    int k4 = K >> 2;
    for (int k = 0; k < k4; k++) {
        float4 a = inr[k], b = wr[k];
        acc += a.x * b.x + a.y * b.y + a.z * b.z + a.w * b.w;
    }
    acc += bias[c];
    if (GELU) acc = 0.5f * acc * (1.0f + erff(acc * 0.70710678118654752f));
    if (RES)  acc += res[idx];
    out[idx] = acc;
}

// ---------------- KV projection as bf16 MFMA GEMM ----------------
// C[131072][512] = ctx[131072][256] @ W[512][256]^T + bias, output bf16 (ushort).
// 128x128 tile, BK=64, 4 waves (2x2), each wave 64x64 = 4x4 fragments of 16x16x32.
__global__ __launch_bounds__(256) void gemm_kv(const float* __restrict__ A,
                                               const float* __restrict__ W,
                                               const float* __restrict__ bias,
                                               ushort* __restrict__ C) {
    int bm = blockIdx.x;   // 0..1023 (row tiles)
    int bn = blockIdx.y;   // 0..3   (col tiles)
    __shared__ __align__(16) ushort As[128 * 72];  // stride 72 u16 = 144B (pad kills 32-way conflict)
    __shared__ __align__(16) ushort Bs[128 * 72];
    int t = threadIdx.x;
    int lane = t & 63;
    int w = t >> 6;
    int wr = w >> 1, wc = w & 1;
    int l15 = lane & 15, lk = lane >> 4;

    f32x4 acc[4][4];
    #pragma unroll
    for (int i = 0; i < 4; i++)
        #pragma unroll
        for (int j = 0; j < 4; j++)
            acc[i][j] = (f32x4){0.f, 0.f, 0.f, 0.f};

    int srow = t >> 3;          // 0..31
    int skk  = (t & 7) * 8;     // 0..56

    for (int kt = 0; kt < 4; ++kt) {
        int kbase = kt * 64;
        // stage A and B tiles (fp32 -> bf16)
        #pragma unroll
        for (int pass = 0; pass < 4; ++pass) {
            int row = pass * 32 + srow;
            const float* ap = A + (size_t)(bm * 128 + row) * 256 + kbase + skk;
            const float* bp = W + (size_t)(bn * 128 + row) * 256 + kbase + skk;
            float4 a0 = *(const float4*)ap;
            float4 a1 = *(const float4*)(ap + 4);
            float4 b0 = *(const float4*)bp;
            float4 b1 = *(const float4*)(bp + 4);
            s16x8 va, vb;
            va[0] = (short)f2bf(a0.x); va[1] = (short)f2bf(a0.y);
            va[2] = (short)f2bf(a0.z); va[3] = (short)f2bf(a0.w);
            va[4] = (short)f2bf(a1.x); va[5] = (short)f2bf(a1.y);
            va[6] = (short)f2bf(a1.z); va[7] = (short)f2bf(a1.w);
            vb[0] = (short)f2bf(b0.x); vb[1] = (short)f2bf(b0.y);
            vb[2] = (short)f2bf(b0.z); vb[3] = (short)f2bf(b0.w);
            vb[4] = (short)f2bf(b1.x); vb[5] = (short)f2bf(b1.y);
            vb[6] = (short)f2bf(b1.z); vb[7] = (short)f2bf(b1.w);
            *(s16x8*)&As[row * 72 + skk] = va;
            *(s16x8*)&Bs[row * 72 + skk] = vb;
        }
        __syncthreads();
        #pragma unroll
        for (int kk = 0; kk < 64; kk += 32) {
            s16x8 af[4], bf[4];
            #pragma unroll
            for (int mi = 0; mi < 4; mi++)
                af[mi] = *(const s16x8*)&As[(wr * 64 + mi * 16 + l15) * 72 + kk + lk * 8];
            #pragma unroll
            for (int ni = 0; ni < 4; ni++)
                bf[ni] = *(const s16x8*)&Bs[(wc * 64 + ni * 16 + l15) * 72 + kk + lk * 8];
            #pragma unroll
            for (int mi = 0; mi < 4; mi++)
                #pragma unroll
                for (int ni = 0; ni < 4; ni++)
                    acc[mi][ni] = __builtin_amdgcn_mfma_f32_16x16x32_bf16(af[mi], bf[ni], acc[mi][ni], 0, 0, 0);
        }
        __syncthreads();
    }
    // epilogue: bias add + bf16 store
    #pragma unroll
    for (int ni = 0; ni < 4; ni++) {
        int col = bn * 128 + wc * 64 + ni * 16 + l15;
        float bv = bias[col];
        #pragma unroll
        for (int mi = 0; mi < 4; mi++) {
            int row0 = bm * 128 + wr * 64 + mi * 16 + lk * 4;
            #pragma unroll
            for (int r = 0; r < 4; r++) {
                C[(size_t)(row0 + r) * 512 + col] = f2bf(acc[mi][ni][r] + bv);
            }
        }
    }
}

// ---------------- Masked cross-attention, 2 query rows per block ----------------
// q: [b,n,256]; kv: ushort bf16 [b,m,512] (k: c<256, v: c>=256); mask int32 [b,n,m]
__global__ __launch_bounds__(256) void xattn2(const float* __restrict__ q,
                                              const ushort* __restrict__ kv,
                                              const int* __restrict__ mask,
                                              float* __restrict__ o) {
    int np = blockIdx.x;     // 0..49
    int h = blockIdx.y, b = blockIdx.z;
    int n0 = np * 2;
    int t = threadIdx.x;
    __shared__ float qs[2][32];
    __shared__ ushort P0[MM];   // 32 KB (dots, then probs, bf16)
    __shared__ ushort P1[MM];   // 32 KB
    __shared__ float red[256];
    __shared__ float ored[2][512];

    if (t < 64) {
        int r = t >> 5, d = t & 31;
        qs[r][d] = q[(size_t)(b * NN + n0 + r) * 256 + h * 32 + d] * SCALE;
    }
    __syncthreads();

    const ushort* kvb = kv + (size_t)b * MM * 512;
    const int* mr0 = mask + (size_t)(b * NN + n0) * MM;
    const int* mr1 = mr0 + MM;

    // pass 1: dots (both rows share K loads) + running max
    float lm0 = -INFINITY, lm1 = -INFINITY;
    for (int m = t; m < MM; m += 256) {
        int k0 = mr0[m], k1 = mr1[m];
        float d0 = -INFINITY, d1 = -INFINITY;
        if (k0 | k1) {
            const uint4* kp = (const uint4*)(kvb + (size_t)m * 512 + h * 32);
            float s0 = 0.f, s1 = 0.f;
            #pragma unroll
            for (int i = 0; i < 4; i++) {
                uint4 u = kp[i];
                float e0 = bf_lo(u.x), e1 = bf_hi(u.x), e2 = bf_lo(u.y), e3 = bf_hi(u.y);
                float e4 = bf_lo(u.z), e5 = bf_hi(u.z), e6 = bf_lo(u.w), e7 = bf_hi(u.w);
                const float* q0 = &qs[0][i * 8];
                const float* q1 = &qs[1][i * 8];
                s0 += q0[0]*e0 + q0[1]*e1 + q0[2]*e2 + q0[3]*e3
                    + q0[4]*e4 + q0[5]*e5 + q0[6]*e6 + q0[7]*e7;
                s1 += q1[0]*e0 + q1[1]*e1 + q1[2]*e2 + q1[3]*e3
                    + q1[4]*e4 + q1[5]*e5 + q1[6]*e6 + q1[7]*e7;
            }
            if (k0) d0 = s0;
            if (k1) d1 = s1;
        }
        P0[m] = f2bf(d0);
        P1[m] = f2bf(d1);
        lm0 = fmaxf(lm0, d0);
        lm1 = fmaxf(lm1, d1);
    }
    red[t] = lm0; __syncthreads();
    for (int s = 128; s > 0; s >>= 1) { if (t < s) red[t] = fmaxf(red[t], red[t + s]); __syncthreads(); }
    float g0 = red[0]; __syncthreads();
    red[t] = lm1; __syncthreads();
    for (int s = 128; s > 0; s >>= 1) { if (t < s) red[t] = fmaxf(red[t], red[t + s]); __syncthreads(); }
    float g1 = red[0]; __syncthreads();

    // pass 2: exp + sum (both rows)
    float ls0 = 0.f, ls1 = 0.f;
    for (int m = t; m < MM; m += 256) {
        float d0 = bf2f(P0[m]);
        float d1 = bf2f(P1[m]);
        float p0 = (d0 == -INFINITY) ? 0.f : __expf(d0 - g0);
        float p1 = (d1 == -INFINITY) ? 0.f : __expf(d1 - g1);
        P0[m] = f2bf(p0);
        P1[m] = f2bf(p1);
        ls0 += p0; ls1 += p1;
    }
    red[t] = ls0; __syncthreads();
    for (int s = 128; s > 0; s >>= 1) { if (t < s) red[t] += red[t + s]; __syncthreads(); }
    float sum0 = red[0]; __syncthreads();
    red[t] = ls1; __syncthreads();
    for (int s = 128; s > 0; s >>= 1) { if (t < s) red[t] += red[t + s]; __syncthreads(); }
    float sum1 = red[0]; __syncthreads();
    float inv0 = 1.f / sum0, inv1 = 1.f / sum1;

    // pass 3: o = P @ V (both rows share V loads); 16 m-groups x 16 d-pairs
    int g = t >> 4, dp = t & 15;
    float a00 = 0.f, a01 = 0.f, a10 = 0.f, a11 = 0.f;
    for (int m = g; m < MM; m += 16) {
        unsigned u = *(const unsigned*)(kvb + (size_t)m * 512 + 256 + h * 32 + 2 * dp);
        float lo = bf_lo(u), hi = bf_hi(u);
        float p0 = bf2f(P0[m]), p1 = bf2f(P1[m]);
        a00 += p0 * lo; a01 += p0 * hi;
        a10 += p1 * lo; a11 += p1 * hi;
    }
    ored[0][g * 32 + 2 * dp]     = a00;
    ored[0][g * 32 + 2 * dp + 1] = a01;
    ored[1][g * 32 + 2 * dp]     = a10;
    ored[1][g * 32 + 2 * dp + 1] = a11;
    __syncthreads();
    if (t < 64) {
        int r = t >> 5, d = t & 31;
        float s = 0.f;
        #pragma unroll
        for (int g2 = 0; g2 < 16; g2++) s += ored[r][g2 * 32 + d];
        o[(size_t)(b * NN + n0 + r) * 256 + h * 32 + d] = s * (r ? inv1 : inv0);
    }
}

// ---------------- Self-attention over seq axis = b (8), one block per n -------------
__global__ void sattn_kernel(const float* __restrict__ qkv, float* __restrict__ so) {
    int n = blockIdx.x;
    int t = threadIdx.x;
    __shared__ float sq[8][256], sk[8][256], sv[8][256];
    __shared__ float S[512];   // [h][i][j]
    for (int idx = t; idx < 8 * 768; idx += 256) {
        int i = idx / 768, c = idx - i * 768;
        float v = qkv[((size_t)(i * NN + n)) * 768 + c];
        if (c < 256) sq[i][c] = v * SCALE;
        else if (c < 512) sk[i][c - 256] = v;
        else sv[i][c - 512] = v;
    }
    __syncthreads();
    for (int idx = t; idx < 512; idx += 256) {
        int h = idx >> 6, i = (idx >> 3) & 7, j = idx & 7;
        float acc = 0.0f;
        #pragma unroll
        for (int d = 0; d < 32; d++) acc += sq[i][h * 32 + d] * sk[j][h * 32 + d];
        S[idx] = acc;
    }
    __syncthreads();
    if (t < 64) {
        int h = t >> 3, i = t & 7;
        float* row = &S[h * 64 + i * 8];
        float mx = row[0];
        #pragma unroll
        for (int j = 1; j < 8; j++) mx = fmaxf(mx, row[j]);
        float sum = 0.0f;
        #pragma unroll
        for (int j = 0; j < 8; j++) { row[j] = __expf(row[j] - mx); sum += row[j]; }
        float inv = 1.0f / sum;
        #pragma unroll
        for (int j = 0; j < 8; j++) row[j] *= inv;
    }
    __syncthreads();
    int c = t, h = t >> 5;
    #pragma unroll
    for (int i = 0; i < 8; i++) {
        float acc = 0.0f;
        #pragma unroll
        for (int j = 0; j < 8; j++) acc += S[h * 64 + i * 8 + j] * sv[j][c];
        so[((size_t)(i * NN + n)) * 256 + c] = acc;
    }
}

extern "C" void kernel_launch(void* const* d_in, const int* in_sizes, int n_in,
                              void* d_out, int out_size, void* d_ws, size_t ws_size,
                              hipStream_t stream) {
    const float* x      = (const float*)d_in[0];
    const float* ctx    = (const float*)d_in[1];
    const int*   mask   = (const int*)  d_in[2];
    const float* mq_w   = (const float*)d_in[3];
    const float* mq_b   = (const float*)d_in[4];
    const float* mkv_w  = (const float*)d_in[5];
    const float* mkv_b  = (const float*)d_in[6];
    const float* mproj_w= (const float*)d_in[7];
    const float* mproj_b= (const float*)d_in[8];
    const float* in_w   = (const float*)d_in[9];
    const float* in_b   = (const float*)d_in[10];
    const float* out_w  = (const float*)d_in[11];
    const float* out_b  = (const float*)d_in[12];
    const float* w1     = (const float*)d_in[13];
    const float* b1     = (const float*)d_in[14];
    const float* w2     = (const float*)d_in[15];
    const float* b2     = (const float*)d_in[16];
    const float* n1_g   = (const float*)d_in[17];
    const float* n1_b   = (const float*)d_in[18];
    const float* n2_g   = (const float*)d_in[19];
    const float* n2_b   = (const float*)d_in[20];
    const float* n3_g   = (const float*)d_in[21];
    const float* n3_b   = (const float*)d_in[22];
    const float* n4_g   = (const float*)d_in[23];
    const float* n4_b   = (const float*)d_in[24];

    float* ws = (float*)d_ws;
    // fp32 workspace layout (floats)
    float* Y1  = ws + 0;         // 204800
    float* Q   = ws + 204800;    // 204800
    float* O   = ws + 409600;    // 204800
    float* X1  = ws + 614400;    // 204800
    float* Y2  = ws + 819200;    // 204800
    float* QKV = ws + 1024000;   // 614400
    float* SO  = ws + 1638400;   // 204800
    float* X2  = ws + 1843200;   // 204800
    float* Y3  = ws + 2048000;   // 204800
    float* F1  = ws + 2252800;   // 1638400
    float* X3  = ws + 3891200;   // 204800
    ushort* KV = (ushort*)((char*)d_ws + 16384000); // 134,217,728 B
    // total ws need ~150.6 MB

    float* out = (float*)d_out;

    // 1) y1 = ln(x, n1)
    ln_kernel<<<ROWS, 256, 0, stream>>>(x, n1_g, n1_b, Y1);
    // 2) q = y1 @ mq_w.T + mq_b
    proj_kernel<false, false><<<(ROWS * 256 + 255) / 256, 256, 0, stream>>>(
        Y1, mq_w, mq_b, nullptr, Q, ROWS, 256, 256);
    // 3) kv = ctx @ mkv_w.T + mkv_b (bf16) — MFMA GEMM
    {
        dim3 grid(CTX_ROWS / 128, 512 / 128);
        gemm_kv<<<grid, 256, 0, stream>>>(ctx, mkv_w, mkv_b, KV);
    }
    // 4) cross-attention (2 query rows per block)
    {
        dim3 grid(NN / 2, HEADSS, BB);
        xattn2<<<grid, 256, 0, stream>>>(Q, KV, mask, O);
    }
    // 5) x1 = x + o @ mproj_w.T + mproj_b
    proj_kernel<false, true><<<(ROWS * 256 + 255) / 256, 256, 0, stream>>>(
        O, mproj_w, mproj_b, x, X1, ROWS, 256, 256);
    // 6) y2 = ln(x1, n2)
    ln_kernel<<<ROWS, 256, 0, stream>>>(X1, n2_g, n2_b, Y2);
    // 7) qkv = y2 @ in_w.T + in_b
    proj_kernel<false, false><<<(ROWS * 768 + 255) / 256, 256, 0, stream>>>(
        Y2, in_w, in_b, nullptr, QKV, ROWS, 256, 768);
    // 8) self-attention over seq axis b
    sattn_kernel<<<NN, 256, 0, stream>>>(QKV, SO);
    // 9) x2 = x1 + so @ out_w.T + out_b
    proj_kernel<false, true><<<(ROWS * 256 + 255) / 256, 256, 0, stream>>>(
        SO, out_w, out_b, X1, X2, ROWS, 256, 256);
    // 10) y3 = ln(x2, n3)
    ln_kernel<<<ROWS, 256, 0, stream>>>(X2, n3_g, n3_b, Y3);
    // 11) f1 = gelu(y3 @ w1.T + b1)
    proj_kernel<true, false><<<(ROWS * FFNN + 255) / 256, 256, 0, stream>>>(
        Y3, w1, b1, nullptr, F1, ROWS, 256, FFNN);
    // 12) x3 = x2 + f1 @ w2.T + b2
    proj_kernel<false, true><<<(ROWS * 256 + 255) / 256, 256, 0, stream>>>(
        F1, w2, b2, X2, X3, ROWS, FFNN, 256);
    // 13) out = ln(x3, n4)
    ln_kernel<<<ROWS, 256, 0, stream>>>(X3, n4_g, n4_b, out);
}

// Round 3
// 1452.259 us; speedup vs baseline: 10.6554x; 2.6466x over previous
//
#include <hip/hip_runtime.h>
#include <hip/hip_bf16.h>

// Problem constants
#define BB 8
#define NN 100
#define DIMM 256
#define HEADSS 8
#define HDD 32
#define FFNN 2048
#define MM 16384               // H*W = 128*128
#define ROWS (BB*NN)           // 800
#define CTX_ROWS (BB*MM)       // 131072
#define SCALE 0.17677669529663689f   // 1/sqrt(32)

typedef __attribute__((ext_vector_type(8))) short s16x8;
typedef __attribute__((ext_vector_type(4))) float f32x4;

__device__ inline ushort f2bf(float f) {
    union { float f; unsigned u; } c; c.f = f;
    unsigned r = c.u + 0x7fffu + ((c.u >> 16) & 1u);
    return (ushort)(r >> 16);
}
__device__ inline float bf2f(ushort u) {
    union { unsigned i; float f; } c; c.i = ((unsigned)u) << 16; return c.f;
}

// ---------------- LayerNorm (dim=256), one block per row ----------------
__global__ void ln_kernel(const float* __restrict__ x, const float* __restrict__ g,
                          const float* __restrict__ beta, float* __restrict__ y) {
    int row = blockIdx.x;
    int t = threadIdx.x;
    float v = x[row * 256 + t];
    __shared__ float red[256];
    red[t] = v; __syncthreads();
    for (int s = 128; s > 0; s >>= 1) { if (t < s) red[t] += red[t + s]; __syncthreads(); }
    float mu = red[0] * (1.0f / 256.0f);
    __syncthreads();
    float d = v - mu;
    red[t] = d * d; __syncthreads();
    for (int s = 128; s > 0; s >>= 1) { if (t < s) red[t] += red[t + s]; __syncthreads(); }
    float var = red[0] * (1.0f / 256.0f);
    float r = rsqrtf(var + 1e-5f);
    y[row * 256 + t] = d * r * g[t] + beta[t];
}

// ---------------- Generic projection: out[r][c] = act(in[r]·w[c] + bias[c]) (+res) ----
template<bool GELU, bool RES>
__global__ void proj_kernel(const float* __restrict__ in, const float* __restrict__ w,
                            const float* __restrict__ bias, const float* __restrict__ res,
                            float* __restrict__ out, int rows, int K, int C) {
    int idx = blockIdx.x * 256 + threadIdx.x;
    if (idx >= rows * C) return;
    int r = idx / C;
    int c = idx - r * C;
    const float4* inr = reinterpret_cast<const float4*>(in + (size_t)r * K);
    const float4* wr  = reinterpret_cast<const float4*>(w  + (size_t)c * K);
    float acc = 0.0f;
    int k4 = K >> 2;
    for (int k = 0; k < k4; k++) {
        float4 a = inr[k], b = wr[k];
        acc += a.x * b.x + a.y * b.y + a.z * b.z + a.w * b.w;
    }
    acc += bias[c];
    if (GELU) acc = 0.5f * acc * (1.0f + erff(acc * 0.70710678118654752f));
    if (RES)  acc += res[idx];
    out[idx] = acc;
}

// ---------------- KV projection as bf16 MFMA GEMM, head-major K/V output ------------
// Kh/Vh[(b*8+h)][m][32] bf16.
__global__ __launch_bounds__(256) void gemm_kv(const float* __restrict__ A,
                                               const float* __restrict__ W,
                                               const float* __restrict__ bias,
                                               ushort* __restrict__ Kh,
                                               ushort* __restrict__ Vh) {
    int bm = blockIdx.x;   // 0..1023 (row tiles)
    int bn = blockIdx.y;   // 0..3   (col tiles)
    __shared__ __align__(16) ushort As[128 * 72];
    __shared__ __align__(16) ushort Bs[128 * 72];
    int t = threadIdx.x;
    int lane = t & 63;
    int w = t >> 6;
    int wr = w >> 1, wc = w & 1;
    int l15 = lane & 15, lk = lane >> 4;

    f32x4 acc[4][4];
    #pragma unroll
    for (int i = 0; i < 4; i++)
        #pragma unroll
        for (int j = 0; j < 4; j++)
            acc[i][j] = (f32x4){0.f, 0.f, 0.f, 0.f};

    int srow = t >> 3;          // 0..31
    int skk  = (t & 7) * 8;     // 0..56

    for (int kt = 0; kt < 4; ++kt) {
        int kbase = kt * 64;
        #pragma unroll
        for (int pass = 0; pass < 4; ++pass) {
            int row = pass * 32 + srow;
            const float* ap = A + (size_t)(bm * 128 + row) * 256 + kbase + skk;
            const float* bp = W + (size_t)(bn * 128 + row) * 256 + kbase + skk;
            float4 a0 = *(const float4*)ap;
            float4 a1 = *(const float4*)(ap + 4);
            float4 b0 = *(const float4*)bp;
            float4 b1 = *(const float4*)(bp + 4);
            s16x8 va, vb;
            va[0] = (short)f2bf(a0.x); va[1] = (short)f2bf(a0.y);
            va[2] = (short)f2bf(a0.z); va[3] = (short)f2bf(a0.w);
            va[4] = (short)f2bf(a1.x); va[5] = (short)f2bf(a1.y);
            va[6] = (short)f2bf(a1.z); va[7] = (short)f2bf(a1.w);
            vb[0] = (short)f2bf(b0.x); vb[1] = (short)f2bf(b0.y);
            vb[2] = (short)f2bf(b0.z); vb[3] = (short)f2bf(b0.w);
            vb[4] = (short)f2bf(b1.x); vb[5] = (short)f2bf(b1.y);
            vb[6] = (short)f2bf(b1.z); vb[7] = (short)f2bf(b1.w);
            *(s16x8*)&As[row * 72 + skk] = va;
            *(s16x8*)&Bs[row * 72 + skk] = vb;
        }
        __syncthreads();
        #pragma unroll
        for (int kk = 0; kk < 64; kk += 32) {
            s16x8 af[4], bf[4];
            #pragma unroll
            for (int mi = 0; mi < 4; mi++)
                af[mi] = *(const s16x8*)&As[(wr * 64 + mi * 16 + l15) * 72 + kk + lk * 8];
            #pragma unroll
            for (int ni = 0; ni < 4; ni++)
                bf[ni] = *(const s16x8*)&Bs[(wc * 64 + ni * 16 + l15) * 72 + kk + lk * 8];
            #pragma unroll
            for (int mi = 0; mi < 4; mi++)
                #pragma unroll
                for (int ni = 0; ni < 4; ni++)
                    acc[mi][ni] = __builtin_amdgcn_mfma_f32_16x16x32_bf16(af[mi], bf[ni], acc[mi][ni], 0, 0, 0);
        }
        __syncthreads();
    }
    // epilogue: bias add + bf16 store, head-major K/V split
    #pragma unroll
    for (int ni = 0; ni < 4; ni++) {
        int col = bn * 128 + wc * 64 + ni * 16 + l15;
        float bv = bias[col];
        int isV = col >> 8;              // 0: K, 1: V
        int c2 = col & 255;
        int h = c2 >> 5, hd = c2 & 31;
        ushort* dst = isV ? Vh : Kh;
        #pragma unroll
        for (int mi = 0; mi < 4; mi++) {
            int row0 = bm * 128 + wr * 64 + mi * 16 + lk * 4;
            #pragma unroll
            for (int r = 0; r < 4; r++) {
                int gr = row0 + r;
                int b = gr >> 14, m = gr & 16383;
                dst[(((size_t)(b * 8 + h)) * 16384 + m) * 32 + hd] = f2bf(acc[mi][ni][r] + bv);
            }
        }
    }
}

// ---------------- Mask bit-pack: Mb[b][n(128 padded)][512] uint32 --------------------
__global__ __launch_bounds__(256) void pack_mask(const int* __restrict__ mask,
                                                 unsigned* __restrict__ Mb) {
    unsigned tid = blockIdx.x * 256 + threadIdx.x;   // up to 2^24
    int b = tid >> 21;
    int rem = tid & ((1u << 21) - 1);
    int n = rem >> 14;
    int m = rem & 16383;
    int mv = 0;
    if (n < 100) mv = mask[(((size_t)b * 100 + n) << 14) + m];
    unsigned long long bal = __ballot(mv != 0);
    if ((threadIdx.x & 63) == 0) {
        size_t widx = (((size_t)b * 128 + n) << 9) + (m >> 5);   // even
        *(unsigned long long*)(Mb + widx) = bal;
    }
}

// ---------------- Flash masked cross-attention (MFMA) -------------------------------
// grid (chunk=8, h=8, b=8), 256 threads (4 waves x 32 q-rows). Each chunk = 2048 kv.
__global__ __launch_bounds__(256) void xattn_flash(
        const float* __restrict__ q,          // [b][100][256]
        const ushort* __restrict__ Kh,        // [(b*8+h)][16384][32]
        const ushort* __restrict__ Vh,
        const unsigned* __restrict__ Mb,      // [b][128][512]
        float* __restrict__ O_part,           // [(b*8+h)*8+ch][128][32]
        float* __restrict__ m_part,           // [(b*8+h)*8+ch][128]
        float* __restrict__ l_part) {
    int ch = blockIdx.x;
    int h = blockIdx.y, b = blockIdx.z;
    int t = threadIdx.x;
    int lane = t & 63, w = t >> 6;
    int l15 = lane & 15, g = lane >> 4;

    __shared__ __align__(16) ushort Qs[128 * 40];   // 10240 B
    __shared__ __align__(16) ushort Ks[64 * 40];    // 5120 B
    __shared__ __align__(16) ushort Vt[32 * 72];    // 4608 B  (V transposed: [d][kv])
    __shared__ __align__(16) ushort Ps[128 * 72];   // 18432 B
    __shared__ unsigned Ms[128 * 64];               // 32768 B

    // ---- stage Q (scaled, bf16, zero-pad rows >= 100) ----
    {
        int r = t >> 1, dh = (t & 1) * 16;
        s16x8 v0 = {0,0,0,0,0,0,0,0}, v1 = {0,0,0,0,0,0,0,0};
        if (r < 100) {
            const float* qp = q + ((size_t)(b * 100 + r)) * 256 + h * 32 + dh;
            #pragma unroll
            for (int j = 0; j < 8; j++) v0[j] = (short)f2bf(qp[j] * SCALE);
            #pragma unroll
            for (int j = 0; j < 8; j++) v1[j] = (short)f2bf(qp[8 + j] * SCALE);
        }
        *(s16x8*)&Qs[r * 40 + dh] = v0;
        *(s16x8*)&Qs[r * 40 + dh + 8] = v1;
    }
    // ---- stage mask chunk: Ms[q][64 words] ----
    {
        const unsigned* mp = Mb + (((size_t)b * 128) << 9) + ch * 64;
        #pragma unroll
        for (int i = 0; i < 32; i++) {
            int idx = t + i * 256;
            int r = idx >> 6, wd = idx & 63;
            Ms[idx] = mp[((size_t)r << 9) + wd];
        }
    }
    __syncthreads();

    // Q fragments (persist in registers)
    s16x8 aq[2];
    aq[0] = *(const s16x8*)&Qs[(w * 32 + l15) * 40 + g * 8];
    aq[1] = *(const s16x8*)&Qs[(w * 32 + 16 + l15) * 40 + g * 8];

    float m_run[2][4], l_run[2][4];
    f32x4 accO[2][2];
    #pragma unroll
    for (int qt = 0; qt < 2; qt++) {
        #pragma unroll
        for (int r = 0; r < 4; r++) { m_run[qt][r] = -1e30f; l_run[qt][r] = 0.f; }
        accO[qt][0] = (f32x4){0.f,0.f,0.f,0.f};
        accO[qt][1] = (f32x4){0.f,0.f,0.f,0.f};
    }

    const ushort* Kbase = Kh + (((size_t)(b * 8 + h)) * 16384 + (size_t)ch * 2048) * 32;
    const ushort* Vbase = Vh + (((size_t)(b * 8 + h)) * 16384 + (size_t)ch * 2048) * 32;

    for (int tile = 0; tile < 32; ++tile) {
        if (tile) __syncthreads();
        // ---- stage K[64][40] and V transposed [32][72] ----
        {
            int mrow = t >> 2, d0 = (t & 3) * 8;
            uint4 k4 = *(const uint4*)(Kbase + ((size_t)(tile * 64 + mrow)) * 32 + d0);
            *(uint4*)&Ks[mrow * 40 + d0] = k4;
            uint4 v4 = *(const uint4*)(Vbase + ((size_t)(tile * 64 + mrow)) * 32 + d0);
            const ushort* vsp = (const ushort*)&v4;
            #pragma unroll
            for (int j = 0; j < 8; j++) Vt[(d0 + j) * 72 + mrow] = vsp[j];
        }
        __syncthreads();

        // ---- QK^T: S[q 32][kv 64] per wave ----
        s16x8 bk[4];
        #pragma unroll
        for (int ni = 0; ni < 4; ni++)
            bk[ni] = *(const s16x8*)&Ks[(ni * 16 + l15) * 40 + g * 8];
        f32x4 sfrag[2][4];
        #pragma unroll
        for (int qt = 0; qt < 2; qt++)
            #pragma unroll
            for (int ni = 0; ni < 4; ni++)
                sfrag[qt][ni] = __builtin_amdgcn_mfma_f32_16x16x32_bf16(
                    aq[qt], bk[ni], (f32x4){0.f,0.f,0.f,0.f}, 0, 0, 0);

        // ---- masked online softmax, write P (bf16) ----
        #pragma unroll
        for (int qt = 0; qt < 2; qt++) {
            #pragma unroll
            for (int r = 0; r < 4; r++) {
                int qrow = w * 32 + qt * 16 + g * 4 + r;
                unsigned wd0 = Ms[qrow * 64 + tile * 2];
                unsigned wd1 = Ms[qrow * 64 + tile * 2 + 1];
                float sv[4];
                float mx = -1e30f;
                #pragma unroll
                for (int ni = 0; ni < 4; ni++) {
                    unsigned wdx = (ni < 2) ? wd0 : wd1;
                    unsigned bit = (wdx >> ((ni & 1) * 16 + l15)) & 1u;
                    sv[ni] = bit ? sfrag[qt][ni][r] : -1e30f;
                    mx = fmaxf(mx, sv[ni]);
                }
                mx = fmaxf(mx, __shfl_xor(mx, 1));
                mx = fmaxf(mx, __shfl_xor(mx, 2));
                mx = fmaxf(mx, __shfl_xor(mx, 4));
                mx = fmaxf(mx, __shfl_xor(mx, 8));
                float mnew = fmaxf(m_run[qt][r], mx);
                float corr = __expf(m_run[qt][r] - mnew);   // exp(-huge)=0, exp(0)=1; no NaN
                m_run[qt][r] = mnew;
                float rowsum = 0.f;
                #pragma unroll
                for (int ni = 0; ni < 4; ni++) {
                    float pv = __expf(sv[ni] - mnew);       // masked -> exp(-huge)=0
                    rowsum += pv;
                    Ps[qrow * 72 + ni * 16 + l15] = f2bf(pv);
                }
                rowsum += __shfl_xor(rowsum, 1);
                rowsum += __shfl_xor(rowsum, 2);
                rowsum += __shfl_xor(rowsum, 4);
                rowsum += __shfl_xor(rowsum, 8);
                l_run[qt][r] = l_run[qt][r] * corr + rowsum;
                accO[qt][0][r] *= corr;
                accO[qt][1][r] *= corr;
            }
        }

        // ---- PV: O[q 32][d 32] += P[q][kv 64] * V[kv][d] ----
        s16x8 ap0[2], ap1[2], bv0[2], bv1[2];
        #pragma unroll
        for (int qt = 0; qt < 2; qt++) {
            ap0[qt] = *(const s16x8*)&Ps[(w * 32 + qt * 16 + l15) * 72 + g * 8];
            ap1[qt] = *(const s16x8*)&Ps[(w * 32 + qt * 16 + l15) * 72 + 32 + g * 8];
        }
        #pragma unroll
        for (int dt = 0; dt < 2; dt++) {
            bv0[dt] = *(const s16x8*)&Vt[(dt * 16 + l15) * 72 + g * 8];
            bv1[dt] = *(const s16x8*)&Vt[(dt * 16 + l15) * 72 + 32 + g * 8];
        }
        #pragma unroll
        for (int qt = 0; qt < 2; qt++)
            #pragma unroll
            for (int dt = 0; dt < 2; dt++) {
                accO[qt][dt] = __builtin_amdgcn_mfma_f32_16x16x32_bf16(ap0[qt], bv0[dt], accO[qt][dt], 0, 0, 0);
                accO[qt][dt] = __builtin_amdgcn_mfma_f32_16x16x32_bf16(ap1[qt], bv1[dt], accO[qt][dt], 0, 0, 0);
            }
    }

    // ---- store partials ----
    size_t pbase = ((size_t)(b * 8 + h) * 8 + ch) * 128;
    #pragma unroll
    for (int qt = 0; qt < 2; qt++) {
        #pragma unroll
        for (int r = 0; r < 4; r++) {
            int qrow = w * 32 + qt * 16 + g * 4 + r;
            #pragma unroll
            for (int dt = 0; dt < 2; dt++)
                O_part[(pbase + qrow) * 32 + dt * 16 + l15] = accO[qt][dt][r];
            if (l15 == 0) {
                m_part[pbase + qrow] = m_run[qt][r];
                l_part[pbase + qrow] = l_run[qt][r];
            }
        }
    }
}

// ---------------- Combine partials: o[b][n][256] -------------------------------------
__global__ __launch_bounds__(256) void xattn_combine(
        const float* __restrict__ O_part, const float* __restrict__ m_part,
        const float* __restrict__ l_part, float* __restrict__ o) {
    int n = blockIdx.x;       // 0..99
    int b = blockIdx.y;
    int t = threadIdx.x;
    int h = t >> 5, d = t & 31;
    size_t base = ((size_t)(b * 8 + h)) * 8;
    float gm = -1e30f;
    #pragma unroll
    for (int ch = 0; ch < 8; ch++)
        gm = fmaxf(gm, m_part[(base + ch) * 128 + n]);
    float L = 0.f, acc = 0.f;
    #pragma unroll
    for (int ch = 0; ch < 8; ch++) {
        float e = __expf(m_part[(base + ch) * 128 + n] - gm);
        L += l_part[(base + ch) * 128 + n] * e;
        acc += O_part[((base + ch) * 128 + n) * 32 + d] * e;
    }
    o[((size_t)(b * 100 + n)) * 256 + t] = acc / L;
}

// ---------------- Self-attention over seq axis = b (8), one block per n -------------
__global__ void sattn_kernel(const float* __restrict__ qkv, float* __restrict__ so) {
    int n = blockIdx.x;
    int t = threadIdx.x;
    __shared__ float sq[8][256], sk[8][256], sv[8][256];
    __shared__ float S[512];   // [h][i][j]
    for (int idx = t; idx < 8 * 768; idx += 256) {
        int i = idx / 768, c = idx - i * 768;
        float v = qkv[((size_t)(i * NN + n)) * 768 + c];
        if (c < 256) sq[i][c] = v * SCALE;
        else if (c < 512) sk[i][c - 256] = v;
        else sv[i][c - 512] = v;
    }
    __syncthreads();
    for (int idx = t; idx < 512; idx += 256) {
        int h = idx >> 6, i = (idx >> 3) & 7, j = idx & 7;
        float acc = 0.0f;
        #pragma unroll
        for (int d = 0; d < 32; d++) acc += sq[i][h * 32 + d] * sk[j][h * 32 + d];
        S[idx] = acc;
    }
    __syncthreads();
    if (t < 64) {
        int h = t >> 3, i = t & 7;
        float* row = &S[h * 64 + i * 8];
        float mx = row[0];
        #pragma unroll
        for (int j = 1; j < 8; j++) mx = fmaxf(mx, row[j]);
        float sum = 0.0f;
        #pragma unroll
        for (int j = 0; j < 8; j++) { row[j] = __expf(row[j] - mx); sum += row[j]; }
        float inv = 1.0f / sum;
        #pragma unroll
        for (int j = 0; j < 8; j++) row[j] *= inv;
    }
    __syncthreads();
    int c = t, h = t >> 5;
    #pragma unroll
    for (int i = 0; i < 8; i++) {
        float acc = 0.0f;
        #pragma unroll
        for (int j = 0; j < 8; j++) acc += S[h * 64 + i * 8 + j] * sv[j][c];
        so[((size_t)(i * NN + n)) * 256 + c] = acc;
    }
}

extern "C" void kernel_launch(void* const* d_in, const int* in_sizes, int n_in,
                              void* d_out, int out_size, void* d_ws, size_t ws_size,
                              hipStream_t stream) {
    const float* x      = (const float*)d_in[0];
    const float* ctx    = (const float*)d_in[1];
    const int*   mask   = (const int*)  d_in[2];
    const float* mq_w   = (const float*)d_in[3];
    const float* mq_b   = (const float*)d_in[4];
    const float* mkv_w  = (const float*)d_in[5];
    const float* mkv_b  = (const float*)d_in[6];
    const float* mproj_w= (const float*)d_in[7];
    const float* mproj_b= (const float*)d_in[8];
    const float* in_w   = (const float*)d_in[9];
    const float* in_b   = (const float*)d_in[10];
    const float* out_w  = (const float*)d_in[11];
    const float* out_b  = (const float*)d_in[12];
    const float* w1     = (const float*)d_in[13];
    const float* b1     = (const float*)d_in[14];
    const float* w2     = (const float*)d_in[15];
    const float* b2     = (const float*)d_in[16];
    const float* n1_g   = (const float*)d_in[17];
    const float* n1_b   = (const float*)d_in[18];
    const float* n2_g   = (const float*)d_in[19];
    const float* n2_b   = (const float*)d_in[20];
    const float* n3_g   = (const float*)d_in[21];
    const float* n3_b   = (const float*)d_in[22];
    const float* n4_g   = (const float*)d_in[23];
    const float* n4_b   = (const float*)d_in[24];

    float* ws = (float*)d_ws;
    // fp32 workspace layout (floats)
    float* Y1  = ws + 0;         // 204800
    float* Q   = ws + 204800;    // 204800
    float* O   = ws + 409600;    // 204800
    float* X1  = ws + 614400;    // 204800
    float* Y2  = ws + 819200;    // 204800
    float* QKV = ws + 1024000;   // 614400
    float* SO  = ws + 1638400;   // 204800
    float* X2  = ws + 1843200;   // 204800
    float* Y3  = ws + 2048000;   // 204800
    float* F1  = ws + 2252800;   // 1638400
    float* X3  = ws + 3891200;   // 204800  -> ends at 4096000 floats (16,384,000 B)
    // transient region during attention (overlaps Y2..F1, which are dead then):
    unsigned* Mb     = (unsigned*)(ws + 819200);   // 524288 words  -> ends 1343488
    float*    O_part = ws + 1343488;               // 2097152       -> ends 3440640
    float*    m_part = ws + 3440640;               // 65536         -> ends 3506176
    float*    l_part = ws + 3506176;               // 65536         -> ends 3571712
    ushort* Kh = (ushort*)((char*)d_ws + 16384000);            // 67,108,864 B
    ushort* Vh = (ushort*)((char*)d_ws + 16384000 + 67108864); // 67,108,864 B

    float* out = (float*)d_out;

    // 1) y1 = ln(x, n1)
    ln_kernel<<<ROWS, 256, 0, stream>>>(x, n1_g, n1_b, Y1);
    // 2) q = y1 @ mq_w.T + mq_b
    proj_kernel<false, false><<<(ROWS * 256 + 255) / 256, 256, 0, stream>>>(
        Y1, mq_w, mq_b, nullptr, Q, ROWS, 256, 256);
    // 3) kv = ctx @ mkv_w.T + mkv_b -> head-major bf16 K/V
    {
        dim3 grid(CTX_ROWS / 128, 512 / 128);
        gemm_kv<<<grid, 256, 0, stream>>>(ctx, mkv_w, mkv_b, Kh, Vh);
    }
    // 3b) pack mask to bits
    pack_mask<<<(BB * 128 * MM) / 256, 256, 0, stream>>>(mask, Mb);
    // 4) flash cross-attention + combine
    {
        dim3 grid(8, HEADSS, BB);
        xattn_flash<<<grid, 256, 0, stream>>>(Q, Kh, Vh, Mb, O_part, m_part, l_part);
        dim3 cgrid(NN, BB);
        xattn_combine<<<cgrid, 256, 0, stream>>>(O_part, m_part, l_part, O);
    }
    // 5) x1 = x + o @ mproj_w.T + mproj_b
    proj_kernel<false, true><<<(ROWS * 256 + 255) / 256, 256, 0, stream>>>(
        O, mproj_w, mproj_b, x, X1, ROWS, 256, 256);
    // 6) y2 = ln(x1, n2)
    ln_kernel<<<ROWS, 256, 0, stream>>>(X1, n2_g, n2_b, Y2);
    // 7) qkv = y2 @ in_w.T + in_b
    proj_kernel<false, false><<<(ROWS * 768 + 255) / 256, 256, 0, stream>>>(
        Y2, in_w, in_b, nullptr, QKV, ROWS, 256, 768);
    // 8) self-attention over seq axis b
    sattn_kernel<<<NN, 256, 0, stream>>>(QKV, SO);
    // 9) x2 = x1 + so @ out_w.T + out_b
    proj_kernel<false, true><<<(ROWS * 256 + 255) / 256, 256, 0, stream>>>(
        SO, out_w, out_b, X1, X2, ROWS, 256, 256);
    // 10) y3 = ln(x2, n3)
    ln_kernel<<<ROWS, 256, 0, stream>>>(X2, n3_g, n3_b, Y3);
    // 11) f1 = gelu(y3 @ w1.T + b1)
    proj_kernel<true, false><<<(ROWS * FFNN + 255) / 256, 256, 0, stream>>>(
        Y3, w1, b1, nullptr, F1, ROWS, 256, FFNN);
    // 12) x3 = x2 + f1 @ w2.T + b2
    proj_kernel<false, true><<<(ROWS * 256 + 255) / 256, 256, 0, stream>>>(
        F1, w2, b2, X2, X3, ROWS, FFNN, 256);
    // 13) out = ln(x3, n4)
    ln_kernel<<<ROWS, 256, 0, stream>>>(X3, n4_g, n4_b, out);
}

// Round 5
// 622.773 us; speedup vs baseline: 24.8477x; 2.3319x over previous
//
#include <hip/hip_runtime.h>
#include <hip/hip_bf16.h>

// Problem constants
#define BB 8
#define NN 100
#define DIMM 256
#define HEADSS 8
#define HDD 32
#define FFNN 2048
#define MM 16384               // H*W = 128*128
#define ROWS (BB*NN)           // 800
#define CTX_ROWS (BB*MM)       // 131072
#define SCALE 0.17677669529663689f   // 1/sqrt(32)

typedef __attribute__((ext_vector_type(8))) short s16x8;
typedef __attribute__((ext_vector_type(4))) float f32x4;

__device__ inline ushort f2bf(float f) {
    union { float f; unsigned u; } c; c.f = f;
    unsigned r = c.u + 0x7fffu + ((c.u >> 16) & 1u);
    return (ushort)(r >> 16);
}
__device__ inline float bf2f(ushort u) {
    union { unsigned i; float f; } c; c.i = ((unsigned)u) << 16; return c.f;
}

// ---------------- LayerNorm (dim=256), one block per row ----------------
__global__ void ln_kernel(const float* __restrict__ x, const float* __restrict__ g,
                          const float* __restrict__ beta, float* __restrict__ y) {
    int row = blockIdx.x;
    int t = threadIdx.x;
    float v = x[row * 256 + t];
    __shared__ float red[256];
    red[t] = v; __syncthreads();
    for (int s = 128; s > 0; s >>= 1) { if (t < s) red[t] += red[t + s]; __syncthreads(); }
    float mu = red[0] * (1.0f / 256.0f);
    __syncthreads();
    float d = v - mu;
    red[t] = d * d; __syncthreads();
    for (int s = 128; s > 0; s >>= 1) { if (t < s) red[t] += red[t + s]; __syncthreads(); }
    float var = red[0] * (1.0f / 256.0f);
    float r = rsqrtf(var + 1e-5f);
    y[row * 256 + t] = d * r * g[t] + beta[t];
}

// ---------------- MFMA projection GEMM: out[M][C] = act(A[M][K] @ W[C][K]^T + bias) (+res)
// BM=64, BN=64, BK=64; 4 waves (2x2), each wave 32x32 = 2x2 fragments of 16x16x32.
template<bool GELU, bool RES>
__global__ __launch_bounds__(256) void gemm_proj(const float* __restrict__ A,
                                                 const float* __restrict__ W,
                                                 const float* __restrict__ bias,
                                                 const float* __restrict__ res,
                                                 float* __restrict__ out,
                                                 int M, int K, int C) {
    int bm = blockIdx.x, bn = blockIdx.y;
    __shared__ __align__(16) ushort As[64 * 72];
    __shared__ __align__(16) ushort Bs[64 * 72];
    int t = threadIdx.x;
    int lane = t & 63, w = t >> 6;
    int wr = w >> 1, wc = w & 1;
    int l15 = lane & 15, lk = lane >> 4;

    f32x4 acc[2][2];
    #pragma unroll
    for (int i = 0; i < 2; i++)
        #pragma unroll
        for (int j = 0; j < 2; j++)
            acc[i][j] = (f32x4){0.f, 0.f, 0.f, 0.f};

    int srow = t >> 2;          // 0..63
    int scol = (t & 3) * 16;    // 0,16,32,48

    int nkt = K >> 6;
    for (int kt = 0; kt < nkt; ++kt) {
        int kb = kt * 64 + scol;
        // stage A (row-guarded) and B
        {
            int gr = bm * 64 + srow;
            s16x8 va0 = {0,0,0,0,0,0,0,0}, va1 = {0,0,0,0,0,0,0,0};
            if (gr < M) {
                const float* ap = A + (size_t)gr * K + kb;
                float4 a0 = *(const float4*)ap;
                float4 a1 = *(const float4*)(ap + 4);
                float4 a2 = *(const float4*)(ap + 8);
                float4 a3 = *(const float4*)(ap + 12);
                va0[0] = (short)f2bf(a0.x); va0[1] = (short)f2bf(a0.y);
                va0[2] = (short)f2bf(a0.z); va0[3] = (short)f2bf(a0.w);
                va0[4] = (short)f2bf(a1.x); va0[5] = (short)f2bf(a1.y);
                va0[6] = (short)f2bf(a1.z); va0[7] = (short)f2bf(a1.w);
                va1[0] = (short)f2bf(a2.x); va1[1] = (short)f2bf(a2.y);
                va1[2] = (short)f2bf(a2.z); va1[3] = (short)f2bf(a2.w);
                va1[4] = (short)f2bf(a3.x); va1[5] = (short)f2bf(a3.y);
                va1[6] = (short)f2bf(a3.z); va1[7] = (short)f2bf(a3.w);
            }
            *(s16x8*)&As[srow * 72 + scol] = va0;
            *(s16x8*)&As[srow * 72 + scol + 8] = va1;
            const float* bp = W + (size_t)(bn * 64 + srow) * K + kb;
            float4 b0 = *(const float4*)bp;
            float4 b1 = *(const float4*)(bp + 4);
            float4 b2 = *(const float4*)(bp + 8);
            float4 b3 = *(const float4*)(bp + 12);
            s16x8 vb0, vb1;
            vb0[0] = (short)f2bf(b0.x); vb0[1] = (short)f2bf(b0.y);
            vb0[2] = (short)f2bf(b0.z); vb0[3] = (short)f2bf(b0.w);
            vb0[4] = (short)f2bf(b1.x); vb0[5] = (short)f2bf(b1.y);
            vb0[6] = (short)f2bf(b1.z); vb0[7] = (short)f2bf(b1.w);
            vb1[0] = (short)f2bf(b2.x); vb1[1] = (short)f2bf(b2.y);
            vb1[2] = (short)f2bf(b2.z); vb1[3] = (short)f2bf(b2.w);
            vb1[4] = (short)f2bf(b3.x); vb1[5] = (short)f2bf(b3.y);
            vb1[6] = (short)f2bf(b3.z); vb1[7] = (short)f2bf(b3.w);
            *(s16x8*)&Bs[srow * 72 + scol] = vb0;
            *(s16x8*)&Bs[srow * 72 + scol + 8] = vb1;
        }
        __syncthreads();
        #pragma unroll
        for (int kk = 0; kk < 64; kk += 32) {
            s16x8 af[2], bf[2];
            #pragma unroll
            for (int mi = 0; mi < 2; mi++)
                af[mi] = *(const s16x8*)&As[(wr * 32 + mi * 16 + l15) * 72 + kk + lk * 8];
            #pragma unroll
            for (int ni = 0; ni < 2; ni++)
                bf[ni] = *(const s16x8*)&Bs[(wc * 32 + ni * 16 + l15) * 72 + kk + lk * 8];
            #pragma unroll
            for (int mi = 0; mi < 2; mi++)
                #pragma unroll
                for (int ni = 0; ni < 2; ni++)
                    acc[mi][ni] = __builtin_amdgcn_mfma_f32_16x16x32_bf16(af[mi], bf[ni], acc[mi][ni], 0, 0, 0);
        }
        __syncthreads();
    }
    // epilogue
    #pragma unroll
    for (int ni = 0; ni < 2; ni++) {
        int col = bn * 64 + wc * 32 + ni * 16 + l15;
        float bv = bias[col];
        #pragma unroll
        for (int mi = 0; mi < 2; mi++) {
            int row0 = bm * 64 + wr * 32 + mi * 16 + lk * 4;
            #pragma unroll
            for (int r = 0; r < 4; r++) {
                int gr = row0 + r;
                if (gr < M) {
                    float v = acc[mi][ni][r] + bv;
                    if (GELU) v = 0.5f * v * (1.0f + erff(v * 0.70710678118654752f));
                    if (RES)  v += res[(size_t)gr * C + col];
                    out[(size_t)gr * C + col] = v;
                }
            }
        }
    }
}

// ---------------- KV projection as bf16 MFMA GEMM, head-major K/V output ------------
// Kh/Vh[(b*8+h)][m][32] bf16.
__global__ __launch_bounds__(256) void gemm_kv(const float* __restrict__ A,
                                               const float* __restrict__ W,
                                               const float* __restrict__ bias,
                                               ushort* __restrict__ Kh,
                                               ushort* __restrict__ Vh) {
    int bm = blockIdx.x;   // 0..1023 (row tiles)
    int bn = blockIdx.y;   // 0..3   (col tiles)
    __shared__ __align__(16) ushort As[128 * 72];
    __shared__ __align__(16) ushort Bs[128 * 72];
    int t = threadIdx.x;
    int lane = t & 63;
    int w = t >> 6;
    int wr = w >> 1, wc = w & 1;
    int l15 = lane & 15, lk = lane >> 4;

    f32x4 acc[4][4];
    #pragma unroll
    for (int i = 0; i < 4; i++)
        #pragma unroll
        for (int j = 0; j < 4; j++)
            acc[i][j] = (f32x4){0.f, 0.f, 0.f, 0.f};

    int srow = t >> 3;          // 0..31
    int skk  = (t & 7) * 8;     // 0..56

    for (int kt = 0; kt < 4; ++kt) {
        int kbase = kt * 64;
        #pragma unroll
        for (int pass = 0; pass < 4; ++pass) {
            int row = pass * 32 + srow;
            const float* ap = A + (size_t)(bm * 128 + row) * 256 + kbase + skk;
            const float* bp = W + (size_t)(bn * 128 + row) * 256 + kbase + skk;
            float4 a0 = *(const float4*)ap;
            float4 a1 = *(const float4*)(ap + 4);
            float4 b0 = *(const float4*)bp;
            float4 b1 = *(const float4*)(bp + 4);
            s16x8 va, vb;
            va[0] = (short)f2bf(a0.x); va[1] = (short)f2bf(a0.y);
            va[2] = (short)f2bf(a0.z); va[3] = (short)f2bf(a0.w);
            va[4] = (short)f2bf(a1.x); va[5] = (short)f2bf(a1.y);
            va[6] = (short)f2bf(a1.z); va[7] = (short)f2bf(a1.w);
            vb[0] = (short)f2bf(b0.x); vb[1] = (short)f2bf(b0.y);
            vb[2] = (short)f2bf(b0.z); vb[3] = (short)f2bf(b0.w);
            vb[4] = (short)f2bf(b1.x); vb[5] = (short)f2bf(b1.y);
            vb[6] = (short)f2bf(b1.z); vb[7] = (short)f2bf(b1.w);
            *(s16x8*)&As[row * 72 + skk] = va;
            *(s16x8*)&Bs[row * 72 + skk] = vb;
        }
        __syncthreads();
        #pragma unroll
        for (int kk = 0; kk < 64; kk += 32) {
            s16x8 af[4], bf[4];
            #pragma unroll
            for (int mi = 0; mi < 4; mi++)
                af[mi] = *(const s16x8*)&As[(wr * 64 + mi * 16 + l15) * 72 + kk + lk * 8];
            #pragma unroll
            for (int ni = 0; ni < 4; ni++)
                bf[ni] = *(const s16x8*)&Bs[(wc * 64 + ni * 16 + l15) * 72 + kk + lk * 8];
            #pragma unroll
            for (int mi = 0; mi < 4; mi++)
                #pragma unroll
                for (int ni = 0; ni < 4; ni++)
                    acc[mi][ni] = __builtin_amdgcn_mfma_f32_16x16x32_bf16(af[mi], bf[ni], acc[mi][ni], 0, 0, 0);
        }
        __syncthreads();
    }
    // epilogue: bias add + bf16 store, head-major K/V split
    #pragma unroll
    for (int ni = 0; ni < 4; ni++) {
        int col = bn * 128 + wc * 64 + ni * 16 + l15;
        float bv = bias[col];
        int isV = col >> 8;              // 0: K, 1: V
        int c2 = col & 255;
        int h = c2 >> 5, hd = c2 & 31;
        ushort* dst = isV ? Vh : Kh;
        #pragma unroll
        for (int mi = 0; mi < 4; mi++) {
            int row0 = bm * 128 + wr * 64 + mi * 16 + lk * 4;
            #pragma unroll
            for (int r = 0; r < 4; r++) {
                int gr = row0 + r;
                int b = gr >> 14, m = gr & 16383;
                dst[(((size_t)(b * 8 + h)) * 16384 + m) * 32 + hd] = f2bf(acc[mi][ni][r] + bv);
            }
        }
    }
}

// ---------------- Mask bit-pack: Mb[b][n(128 padded)][512] uint32 --------------------
__global__ __launch_bounds__(256) void pack_mask(const int* __restrict__ mask,
                                                 unsigned* __restrict__ Mb) {
    unsigned tid = blockIdx.x * 256 + threadIdx.x;   // up to 2^24
    int b = tid >> 21;
    int rem = tid & ((1u << 21) - 1);
    int n = rem >> 14;
    int m = rem & 16383;
    int mv = 0;
    if (n < 100) mv = mask[(((size_t)b * 100 + n) << 14) + m];
    unsigned long long bal = __ballot(mv != 0);
    if ((threadIdx.x & 63) == 0) {
        size_t widx = (((size_t)b * 128 + n) << 9) + (m >> 5);   // even
        *(unsigned long long*)(Mb + widx) = bal;
    }
}

// ---------------- Flash masked cross-attention (MFMA) -------------------------------
// grid (chunk=8, h=8, b=8), 256 threads (4 waves x 32 q-rows). Each chunk = 2048 kv.
__global__ __launch_bounds__(256) void xattn_flash(
        const float* __restrict__ q,          // [b][100][256]
        const ushort* __restrict__ Kh,        // [(b*8+h)][16384][32]
        const ushort* __restrict__ Vh,
        const unsigned* __restrict__ Mb,      // [b][128][512]
        float* __restrict__ O_part,           // [(b*8+h)*8+ch][128][32]
        float* __restrict__ m_part,           // [(b*8+h)*8+ch][128]
        float* __restrict__ l_part) {
    int ch = blockIdx.x;
    int h = blockIdx.y, b = blockIdx.z;
    int t = threadIdx.x;
    int lane = t & 63, w = t >> 6;
    int l15 = lane & 15, g = lane >> 4;

    __shared__ __align__(16) ushort Qs[128 * 40];   // 10240 B
    __shared__ __align__(16) ushort Ks[64 * 40];    // 5120 B
    __shared__ __align__(16) ushort Vt[32 * 72];    // 4608 B  (V transposed: [d][kv])
    __shared__ __align__(16) ushort Ps[128 * 72];   // 18432 B
    __shared__ unsigned Ms[128 * 64];               // 32768 B

    // ---- stage Q (scaled, bf16, zero-pad rows >= 100) ----
    {
        int r = t >> 1, dh = (t & 1) * 16;
        s16x8 v0 = {0,0,0,0,0,0,0,0}, v1 = {0,0,0,0,0,0,0,0};
        if (r < 100) {
            const float* qp = q + ((size_t)(b * 100 + r)) * 256 + h * 32 + dh;
            #pragma unroll
            for (int j = 0; j < 8; j++) v0[j] = (short)f2bf(qp[j] * SCALE);
            #pragma unroll
            for (int j = 0; j < 8; j++) v1[j] = (short)f2bf(qp[8 + j] * SCALE);
        }
        *(s16x8*)&Qs[r * 40 + dh] = v0;
        *(s16x8*)&Qs[r * 40 + dh + 8] = v1;
    }
    // ---- stage mask chunk: Ms[q][64 words] ----
    {
        const unsigned* mp = Mb + (((size_t)b * 128) << 9) + ch * 64;
        #pragma unroll
        for (int i = 0; i < 32; i++) {
            int idx = t + i * 256;
            int r = idx >> 6, wd = idx & 63;
            Ms[idx] = mp[((size_t)r << 9) + wd];
        }
    }
    __syncthreads();

    // Q fragments (persist in registers)
    s16x8 aq[2];
    aq[0] = *(const s16x8*)&Qs[(w * 32 + l15) * 40 + g * 8];
    aq[1] = *(const s16x8*)&Qs[(w * 32 + 16 + l15) * 40 + g * 8];

    float m_run[2][4], l_run[2][4];
    f32x4 accO[2][2];
    #pragma unroll
    for (int qt = 0; qt < 2; qt++) {
        #pragma unroll
        for (int r = 0; r < 4; r++) { m_run[qt][r] = -1e30f; l_run[qt][r] = 0.f; }
        accO[qt][0] = (f32x4){0.f,0.f,0.f,0.f};
        accO[qt][1] = (f32x4){0.f,0.f,0.f,0.f};
    }

    const ushort* Kbase = Kh + (((size_t)(b * 8 + h)) * 16384 + (size_t)ch * 2048) * 32;
    const ushort* Vbase = Vh + (((size_t)(b * 8 + h)) * 16384 + (size_t)ch * 2048) * 32;

    for (int tile = 0; tile < 32; ++tile) {
        if (tile) __syncthreads();
        // ---- stage K[64][40] and V transposed [32][72] ----
        {
            int mrow = t >> 2, d0 = (t & 3) * 8;
            uint4 k4 = *(const uint4*)(Kbase + ((size_t)(tile * 64 + mrow)) * 32 + d0);
            *(uint4*)&Ks[mrow * 40 + d0] = k4;
            uint4 v4 = *(const uint4*)(Vbase + ((size_t)(tile * 64 + mrow)) * 32 + d0);
            const ushort* vsp = (const ushort*)&v4;
            #pragma unroll
            for (int j = 0; j < 8; j++) Vt[(d0 + j) * 72 + mrow] = vsp[j];
        }
        __syncthreads();

        // ---- QK^T: S[q 32][kv 64] per wave ----
        s16x8 bk[4];
        #pragma unroll
        for (int ni = 0; ni < 4; ni++)
            bk[ni] = *(const s16x8*)&Ks[(ni * 16 + l15) * 40 + g * 8];
        f32x4 sfrag[2][4];
        #pragma unroll
        for (int qt = 0; qt < 2; qt++)
            #pragma unroll
            for (int ni = 0; ni < 4; ni++)
                sfrag[qt][ni] = __builtin_amdgcn_mfma_f32_16x16x32_bf16(
                    aq[qt], bk[ni], (f32x4){0.f,0.f,0.f,0.f}, 0, 0, 0);

        // ---- masked online softmax, write P (bf16) ----
        #pragma unroll
        for (int qt = 0; qt < 2; qt++) {
            #pragma unroll
            for (int r = 0; r < 4; r++) {
                int qrow = w * 32 + qt * 16 + g * 4 + r;
                unsigned wd0 = Ms[qrow * 64 + tile * 2];
                unsigned wd1 = Ms[qrow * 64 + tile * 2 + 1];
                float sv[4];
                float mx = -1e30f;
                #pragma unroll
                for (int ni = 0; ni < 4; ni++) {
                    unsigned wdx = (ni < 2) ? wd0 : wd1;
                    unsigned bit = (wdx >> ((ni & 1) * 16 + l15)) & 1u;
                    sv[ni] = bit ? sfrag[qt][ni][r] : -1e30f;
                    mx = fmaxf(mx, sv[ni]);
                }
                mx = fmaxf(mx, __shfl_xor(mx, 1));
                mx = fmaxf(mx, __shfl_xor(mx, 2));
                mx = fmaxf(mx, __shfl_xor(mx, 4));
                mx = fmaxf(mx, __shfl_xor(mx, 8));
                float mnew = fmaxf(m_run[qt][r], mx);
                float corr = __expf(m_run[qt][r] - mnew);   // exp(-huge)=0, exp(0)=1; no NaN
                m_run[qt][r] = mnew;
                float rowsum = 0.f;
                #pragma unroll
                for (int ni = 0; ni < 4; ni++) {
                    float pv = __expf(sv[ni] - mnew);       // masked -> exp(-huge)=0
                    rowsum += pv;
                    Ps[qrow * 72 + ni * 16 + l15] = f2bf(pv);
                }
                rowsum += __shfl_xor(rowsum, 1);
                rowsum += __shfl_xor(rowsum, 2);
                rowsum += __shfl_xor(rowsum, 4);
                rowsum += __shfl_xor(rowsum, 8);
                l_run[qt][r] = l_run[qt][r] * corr + rowsum;
                accO[qt][0][r] *= corr;
                accO[qt][1][r] *= corr;
            }
        }

        // ---- PV: O[q 32][d 32] += P[q][kv 64] * V[kv][d] ----
        s16x8 ap0[2], ap1[2], bv0[2], bv1[2];
        #pragma unroll
        for (int qt = 0; qt < 2; qt++) {
            ap0[qt] = *(const s16x8*)&Ps[(w * 32 + qt * 16 + l15) * 72 + g * 8];
            ap1[qt] = *(const s16x8*)&Ps[(w * 32 + qt * 16 + l15) * 72 + 32 + g * 8];
        }
        #pragma unroll
        for (int dt = 0; dt < 2; dt++) {
            bv0[dt] = *(const s16x8*)&Vt[(dt * 16 + l15) * 72 + g * 8];
            bv1[dt] = *(const s16x8*)&Vt[(dt * 16 + l15) * 72 + 32 + g * 8];
        }
        #pragma unroll
        for (int qt = 0; qt < 2; qt++)
            #pragma unroll
            for (int dt = 0; dt < 2; dt++) {
                accO[qt][dt] = __builtin_amdgcn_mfma_f32_16x16x32_bf16(ap0[qt], bv0[dt], accO[qt][dt], 0, 0, 0);
                accO[qt][dt] = __builtin_amdgcn_mfma_f32_16x16x32_bf16(ap1[qt], bv1[dt], accO[qt][dt], 0, 0, 0);
            }
    }

    // ---- store partials ----
    size_t pbase = ((size_t)(b * 8 + h) * 8 + ch) * 128;
    #pragma unroll
    for (int qt = 0; qt < 2; qt++) {
        #pragma unroll
        for (int r = 0; r < 4; r++) {
            int qrow = w * 32 + qt * 16 + g * 4 + r;
            #pragma unroll
            for (int dt = 0; dt < 2; dt++)
                O_part[(pbase + qrow) * 32 + dt * 16 + l15] = accO[qt][dt][r];
            if (l15 == 0) {
                m_part[pbase + qrow] = m_run[qt][r];
                l_part[pbase + qrow] = l_run[qt][r];
            }
        }
    }
}

// ---------------- Combine partials: o[b][n][256] -------------------------------------
__global__ __launch_bounds__(256) void xattn_combine(
        const float* __restrict__ O_part, const float* __restrict__ m_part,
        const float* __restrict__ l_part, float* __restrict__ o) {
    int n = blockIdx.x;       // 0..99
    int b = blockIdx.y;
    int t = threadIdx.x;
    int h = t >> 5, d = t & 31;
    size_t base = ((size_t)(b * 8 + h)) * 8;
    float gm = -1e30f;
    #pragma unroll
    for (int ch = 0; ch < 8; ch++)
        gm = fmaxf(gm, m_part[(base + ch) * 128 + n]);
    float L = 0.f, acc = 0.f;
    #pragma unroll
    for (int ch = 0; ch < 8; ch++) {
        float e = __expf(m_part[(base + ch) * 128 + n] - gm);
        L += l_part[(base + ch) * 128 + n] * e;
        acc += O_part[((base + ch) * 128 + n) * 32 + d] * e;
    }
    o[((size_t)(b * 100 + n)) * 256 + t] = acc / L;
}

// ---------------- Self-attention over seq axis = b (8), one block per n -------------
__global__ void sattn_kernel(const float* __restrict__ qkv, float* __restrict__ so) {
    int n = blockIdx.x;
    int t = threadIdx.x;
    __shared__ float sq[8][256], sk[8][256], sv[8][256];
    __shared__ float S[512];   // [h][i][j]
    for (int idx = t; idx < 8 * 768; idx += 256) {
        int i = idx / 768, c = idx - i * 768;
        float v = qkv[((size_t)(i * NN + n)) * 768 + c];
        if (c < 256) sq[i][c] = v * SCALE;
        else if (c < 512) sk[i][c - 256] = v;
        else sv[i][c - 512] = v;
    }
    __syncthreads();
    for (int idx = t; idx < 512; idx += 256) {
        int h = idx >> 6, i = (idx >> 3) & 7, j = idx & 7;
        float acc = 0.0f;
        #pragma unroll
        for (int d = 0; d < 32; d++) acc += sq[i][h * 32 + d] * sk[j][h * 32 + d];
        S[idx] = acc;
    }
    __syncthreads();
    if (t < 64) {
        int h = t >> 3, i = t & 7;
        float* row = &S[h * 64 + i * 8];
        float mx = row[0];
        #pragma unroll
        for (int j = 1; j < 8; j++) mx = fmaxf(mx, row[j]);
        float sum = 0.0f;
        #pragma unroll
        for (int j = 0; j < 8; j++) { row[j] = __expf(row[j] - mx); sum += row[j]; }
        float inv = 1.0f / sum;
        #pragma unroll
        for (int j = 0; j < 8; j++) row[j] *= inv;
    }
    __syncthreads();
    int c = t, h = t >> 5;
    #pragma unroll
    for (int i = 0; i < 8; i++) {
        float acc = 0.0f;
        #pragma unroll
        for (int j = 0; j < 8; j++) acc += S[h * 64 + i * 8 + j] * sv[j][c];
        so[((size_t)(i * NN + n)) * 256 + c] = acc;
    }
}

extern "C" void kernel_launch(void* const* d_in, const int* in_sizes, int n_in,
                              void* d_out, int out_size, void* d_ws, size_t ws_size,
                              hipStream_t stream) {
    const float* x      = (const float*)d_in[0];
    const float* ctx    = (const float*)d_in[1];
    const int*   mask   = (const int*)  d_in[2];
    const float* mq_w   = (const float*)d_in[3];
    const float* mq_b   = (const float*)d_in[4];
    const float* mkv_w  = (const float*)d_in[5];
    const float* mkv_b  = (const float*)d_in[6];
    const float* mproj_w= (const float*)d_in[7];
    const float* mproj_b= (const float*)d_in[8];
    const float* in_w   = (const float*)d_in[9];
    const float* in_b   = (const float*)d_in[10];
    const float* out_w  = (const float*)d_in[11];
    const float* out_b  = (const float*)d_in[12];
    const float* w1     = (const float*)d_in[13];
    const float* b1     = (const float*)d_in[14];
    const float* w2     = (const float*)d_in[15];
    const float* b2     = (const float*)d_in[16];
    const float* n1_g   = (const float*)d_in[17];
    const float* n1_b   = (const float*)d_in[18];
    const float* n2_g   = (const float*)d_in[19];
    const float* n2_b   = (const float*)d_in[20];
    const float* n3_g   = (const float*)d_in[21];
    const float* n3_b   = (const float*)d_in[22];
    const float* n4_g   = (const float*)d_in[23];
    const float* n4_b   = (const float*)d_in[24];

    float* ws = (float*)d_ws;
    // fp32 workspace layout (floats)
    float* Y1  = ws + 0;         // 204800
    float* Q   = ws + 204800;    // 204800
    float* O   = ws + 409600;    // 204800
    float* X1  = ws + 614400;    // 204800
    float* Y2  = ws + 819200;    // 204800
    float* QKV = ws + 1024000;   // 614400
    float* SO  = ws + 1638400;   // 204800
    float* X2  = ws + 1843200;   // 204800
    float* Y3  = ws + 2048000;   // 204800
    float* F1  = ws + 2252800;   // 1638400
    float* X3  = ws + 3891200;   // 204800  -> ends at 4096000 floats (16,384,000 B)
    // transient region during attention (overlaps Y2..F1, which are dead then):
    unsigned* Mb     = (unsigned*)(ws + 819200);   // 524288 words  -> ends 1343488
    float*    O_part = ws + 1343488;               // 2097152       -> ends 3440640
    float*    m_part = ws + 3440640;               // 65536         -> ends 3506176
    float*    l_part = ws + 3506176;               // 65536         -> ends 3571712
    ushort* Kh = (ushort*)((char*)d_ws + 16384000);            // 67,108,864 B
    ushort* Vh = (ushort*)((char*)d_ws + 16384000 + 67108864); // 67,108,864 B

    float* out = (float*)d_out;

    // 1) y1 = ln(x, n1)
    ln_kernel<<<ROWS, 256, 0, stream>>>(x, n1_g, n1_b, Y1);
    // 2) q = y1 @ mq_w.T + mq_b
    gemm_proj<false, false><<<dim3(13, 4), 256, 0, stream>>>(
        Y1, mq_w, mq_b, nullptr, Q, ROWS, 256, 256);
    // 3) kv = ctx @ mkv_w.T + mkv_b -> head-major bf16 K/V
    {
        dim3 grid(CTX_ROWS / 128, 512 / 128);
        gemm_kv<<<grid, 256, 0, stream>>>(ctx, mkv_w, mkv_b, Kh, Vh);
    }
    // 3b) pack mask to bits
    pack_mask<<<(BB * 128 * MM) / 256, 256, 0, stream>>>(mask, Mb);
    // 4) flash cross-attention + combine
    {
        dim3 grid(8, HEADSS, BB);
        xattn_flash<<<grid, 256, 0, stream>>>(Q, Kh, Vh, Mb, O_part, m_part, l_part);
        dim3 cgrid(NN, BB);
        xattn_combine<<<cgrid, 256, 0, stream>>>(O_part, m_part, l_part, O);
    }
    // 5) x1 = x + o @ mproj_w.T + mproj_b
    gemm_proj<false, true><<<dim3(13, 4), 256, 0, stream>>>(
        O, mproj_w, mproj_b, x, X1, ROWS, 256, 256);
    // 6) y2 = ln(x1, n2)
    ln_kernel<<<ROWS, 256, 0, stream>>>(X1, n2_g, n2_b, Y2);
    // 7) qkv = y2 @ in_w.T + in_b
    gemm_proj<false, false><<<dim3(13, 12), 256, 0, stream>>>(
        Y2, in_w, in_b, nullptr, QKV, ROWS, 256, 768);
    // 8) self-attention over seq axis b
    sattn_kernel<<<NN, 256, 0, stream>>>(QKV, SO);
    // 9) x2 = x1 + so @ out_w.T + out_b
    gemm_proj<false, true><<<dim3(13, 4), 256, 0, stream>>>(
        SO, out_w, out_b, X1, X2, ROWS, 256, 256);
    // 10) y3 = ln(x2, n3)
    ln_kernel<<<ROWS, 256, 0, stream>>>(X2, n3_g, n3_b, Y3);
    // 11) f1 = gelu(y3 @ w1.T + b1)
    gemm_proj<true, false><<<dim3(13, 32), 256, 0, stream>>>(
        Y3, w1, b1, nullptr, F1, ROWS, 256, FFNN);
    // 12) x3 = x2 + f1 @ w2.T + b2
    gemm_proj<false, true><<<dim3(13, 4), 256, 0, stream>>>(
        F1, w2, b2, X2, X3, ROWS, FFNN, 256);
    // 13) out = ln(x3, n4)
    ln_kernel<<<ROWS, 256, 0, stream>>>(X3, n4_g, n4_b, out);
}